// Round 21
// baseline (277.844 us; speedup 1.0000x reference)
//
#include <hip/hip_runtime.h>
#include <hip/hip_bf16.h>
#include <math.h>

// ProtoInstanceMultiCrossAttention: C=10, S=10, NQ=30, H=1024
#define C_   10
#define S_   10
#define NQ_  30
#define H_   1024
#define Q_   300
#define ROWS_ 400

typedef __attribute__((ext_vector_type(8))) short s16x8;    // 8 bf16 (4 VGPRs)
typedef __attribute__((ext_vector_type(4))) float f32x4;    // MFMA acc

static __device__ __forceinline__ short f2b(float f) {
  __hip_bfloat16 h = __float2bfloat16(f);
  return __builtin_bit_cast(short, h);
}

static __device__ __forceinline__ float ftanh(float v) {
  v = fminf(fmaxf(v, -10.f), 10.f);
  float e = __expf(2.f * v);
  return (e - 1.f) / (e + 1.f);
}

// ---------------------------------------------------------------------------
// Kernel 1 (merged, 512 thr): blocks [0,400): f = x@W1+b1, 4-row x 256-col
// tiles (thread = (col, row-pair), W column read feeds 4 rows -> half L2
// traffic); blocks [400,912): trans Bt[mat][n][k] = bf16(W[k][n]);
// block 912: zero logits.
// ---------------------------------------------------------------------------
__global__ __launch_bounds__(512) void feat_trans_kernel(
    const float* __restrict__ x, const float* __restrict__ W1,
    const float* __restrict__ b1, const float* __restrict__ W2,
    float* __restrict__ f, unsigned short* __restrict__ Bt,
    float* __restrict__ logits) {
  __shared__ char lsbuf[64 * 65 * 4];  // overlaid: xs[4][1024] / tl[64][65]
  const int bi = blockIdx.x;
  const int tid = threadIdx.x;

  if (bi < 400) {
    // ---- feat: f = x @ W1 + b1  (4 rows, 256 cols)
    float (*xs)[H_] = (float (*)[H_])lsbuf;
    const int rt = bi % 100;
    const int nt = bi / 100;
    const int r0 = rt * 4;
    const int n0 = nt * 256;

    for (int t = tid; t < 4 * H_ / 4; t += 512) {
      int r = t >> 8, h4 = (t & 255) * 4;
      *(float4*)&xs[r][h4] = *(const float4*)&x[(size_t)(r0 + r) * H_ + h4];
    }
    __syncthreads();

    const int col = tid & 255;
    const int rh = tid >> 8;           // 0 or 1 -> rows rh*2, rh*2+1
    float acc0 = 0.f, acc1 = 0.f;
    const float* __restrict__ wp = W1 + n0 + col;
    const float* __restrict__ x0 = xs[rh * 2];
    const float* __restrict__ x1 = xs[rh * 2 + 1];
#pragma unroll 16
    for (int h = 0; h < H_; ++h) {
      float w = wp[(size_t)h * H_];
      acc0 = fmaf(x0[h], w, acc0);
      acc1 = fmaf(x1[h], w, acc1);
    }
    const int gcol = n0 + col;
    const float bb = b1[gcol];
    f[(size_t)(r0 + rh * 2 + 0) * H_ + gcol] = acc0 + bb;
    f[(size_t)(r0 + rh * 2 + 1) * H_ + gcol] = acc1 + bb;
    return;
  }

  if (bi == 912) {
    float4* lz = (float4*)logits;
    for (int i = tid; i < 7500; i += 512) lz[i] = make_float4(0.f, 0.f, 0.f, 0.f);
    return;
  }

  // ---- trans: Bt[mat][n][k] = bf16(W[k][n])  (512 thr, 64x64 tile)
  {
    float (*tl)[65] = (float (*)[65])lsbuf;
    const int b = bi - 400;
    const int mat = b >> 8, kt = (b >> 4) & 15, ntl = b & 15;
    const float* __restrict__ src =
        W2 + (size_t)(2 + mat) * H_ * H_ + (size_t)(kt * 64) * H_ + ntl * 64;
    {
      int r = tid >> 3, c8 = (tid & 7) * 8;
      const float* srcp = src + (size_t)r * H_ + c8;
#pragma unroll
      for (int j = 0; j < 2; ++j) {
        float4 v = *(const float4*)(srcp + j * 4);
        tl[r][c8 + j * 4 + 0] = v.x;
        tl[r][c8 + j * 4 + 1] = v.y;
        tl[r][c8 + j * 4 + 2] = v.z;
        tl[r][c8 + j * 4 + 3] = v.w;
      }
    }
    __syncthreads();
    {
      int n = tid >> 3, k0t = (tid & 7) * 8;
      s16x8 o0;
#pragma unroll
      for (int j = 0; j < 8; ++j) o0[j] = f2b(tl[k0t + j][n]);
      unsigned short* dstp = Bt + (size_t)mat * H_ * H_ +
                             (size_t)(ntl * 64 + n) * H_ + kt * 64 + k0t;
      *(s16x8*)dstp = o0;
    }
  }
}

// ---------------------------------------------------------------------------
// Kernel 2 (512 thr): a_s = sf @ Ws (100 rows), a_q = qf @ Wq + b2 (300 rows).
// 4-row x 256-col tiles; grid 100 rt (25 sup + 75 qry) x 4 nt = 400 blocks.
// ---------------------------------------------------------------------------
__global__ __launch_bounds__(512) void proj_kernel(
    const float* __restrict__ f, const float* __restrict__ W2,
    const float* __restrict__ b2, float* __restrict__ a) {
  __shared__ float fs[4][H_];
  const int rt = blockIdx.x % 100;
  const int nt = blockIdx.x / 100;
  const bool isSup = (rt < 25);
  const int i0 = isSup ? rt * 4 : (rt - 25) * 4;
  const int n0 = nt * 256;
  const float* __restrict__ W = isSup ? W2 : (W2 + (size_t)H_ * H_);
  const int tid = threadIdx.x;

  for (int t = tid; t < 4 * H_ / 4; t += 512) {
    int r = t >> 8, h4 = (t & 255) * 4;
    int i = i0 + r;
    int row = isSup ? ((i / 10) * 40 + (i % 10)) : ((i / 30) * 40 + 10 + (i % 30));
    *(float4*)&fs[r][h4] = *(const float4*)&f[(size_t)row * H_ + h4];
  }
  __syncthreads();

  const int col = tid & 255;
  const int rh = tid >> 8;
  float acc0 = 0.f, acc1 = 0.f;
  const float* __restrict__ wp = W + n0 + col;
  const float* __restrict__ f0 = fs[rh * 2];
  const float* __restrict__ f1 = fs[rh * 2 + 1];
#pragma unroll 16
  for (int h = 0; h < H_; ++h) {
    float w = wp[(size_t)h * H_];
    acc0 = fmaf(f0[h], w, acc0);
    acc1 = fmaf(f1[h], w, acc1);
  }
  const int gcol = n0 + col;
  const float bb = isSup ? 0.f : b2[gcol];
  const int o0 = (isSup ? i0 : (100 + i0)) + rh * 2;
  a[(size_t)(o0 + 0) * H_ + gcol] = acc0 + bb;
  a[(size_t)(o0 + 1) * H_ + gcol] = acc1 + bb;
}

// ---------------------------------------------------------------------------
// Kernel 3 (dominant): bf16 MFMA fused mca — reg-generated A (R10 structure),
// launch_bounds (256,3): VGPR 84, ~3 blocks/CU.  [best-known: ~186 us]
// ---------------------------------------------------------------------------
__global__ __launch_bounds__(256, 3) void mca_mfma_kernel(
    const float* __restrict__ f, const float* __restrict__ a,
    const unsigned short* __restrict__ Bt, float* __restrict__ logits) {
  const int b = blockIdx.x;
  const int nt = b & 7;
  const int qt = (b >> 3) % 19;
  const int c = (b >> 3) / 19;
  const int q0 = qt * 16;
  const int n0 = nt * 128;

  __shared__ unsigned short Bls[2][128 * 64];  // 2 x 16 KB, XOR-swizzled rows
  __shared__ float sl[2][26][36];              // 2 x 3744 B (144 B rows)

  const int tid = threadIdx.x;
  const int w = tid >> 6, lane = tid & 63;
  const int frow = lane & 15;   // qloc AND D-col
  const int lq = lane >> 4;     // k-segment (8 f32)
  const int wr = w >> 1, wc = w & 1;

  // ---- STAGE: 208 threads, one float4 (26 rows x 32 f32)
  const int str = tid >> 3, sseg = tid & 7;
  int sgrow;
  if (str < 10) sgrow = c * 40 + str;
  else {
    int qg = q0 + (str - 10);
    if (qg > 299) qg = 299;
    sgrow = (qg / 30) * 40 + 10 + (qg % 30);
  }
  const float* fb_stage = f + (size_t)sgrow * H_ + sseg * 4;
  const unsigned st_off = (unsigned)(str * 144 + sseg * 16);

  // ---- sl read offsets (bytes)
  const unsigned qfo = (unsigned)((10 + frow) * 144 + lq * 32);
  unsigned sfo[5];
#pragma unroll
  for (int m = 0; m < 5; ++m) sfo[m] = (unsigned)((wr * 5 + m) * 144 + lq * 32);

  // ---- B DMA setup (linear LDS dest, inverse-swizzled source)
  const int rlo = lane >> 3;
  const int cch = (lane & 7) ^ rlo;
  const unsigned short* bsrc[4];
  unsigned bldso[4];
#pragma unroll
  for (int i = 0; i < 4; ++i) {
    int row = w * 32 + i * 8 + rlo;
    bsrc[i] = Bt + (size_t)(cch >> 2) * H_ * H_ + (size_t)(n0 + row) * H_ +
              (cch & 3) * 8;
    bldso[i] = (unsigned)(w * 4096 + i * 1024);
  }

  // ---- B frag read offsets
  const unsigned fkb = (unsigned)(lq * 16);
  const unsigned swf = (unsigned)((frow & 7) << 4);
  unsigned brd[4];
#pragma unroll
  for (int nf = 0; nf < 4; ++nf) brd[nf] = (unsigned)((wc * 64 + nf * 16 + frow) * 128);

  f32x4 acc[5][4];
#pragma unroll
  for (int m = 0; m < 5; ++m)
#pragma unroll
    for (int nf = 0; nf < 4; ++nf) acc[m][nf] = (f32x4)(0.f);

#define STAGE(SLP, KS)                                                         \
  do {                                                                         \
    if (tid < 208) {                                                           \
      float4 v = *(const float4*)(fb_stage + (KS) * 32);                       \
      *(float4*)((char*)&sl[SLP][0][0] + st_off) = v;                          \
    }                                                                          \
  } while (0)

#define DMA_B(P, KG)                                                           \
  do {                                                                         \
    _Pragma("unroll") for (int i = 0; i < 4; ++i) {                            \
      __builtin_amdgcn_global_load_lds(                                        \
          (const __attribute__((address_space(1))) unsigned int*)(bsrc[i] + (KG)), \
          (__attribute__((address_space(3))) unsigned int*)((char*)&Bls[P][0] + bldso[i]), \
          16, 0, 0);                                                           \
    }                                                                          \
  } while (0)

// One K-step: hoist 8 B-frags; per m generate t1/t2 and consume immediately.
#define STEP_BODY(P)                                                           \
  do {                                                                         \
    const char* SLB = (const char*)&sl[P][0][0];                               \
    const char* BB = (const char*)&Bls[P][0];                                  \
    float4 qa = *(const float4*)(SLB + qfo);                                   \
    float4 qb = *(const float4*)(SLB + qfo + 16);                              \
    s16x8 bf0 = *(const s16x8*)(BB + ((brd[0] + fkb) ^ swf));                  \
    s16x8 bf1 = *(const s16x8*)(BB + ((brd[1] + fkb) ^ swf));                  \
    s16x8 bf2 = *(const s16x8*)(BB + ((brd[2] + fkb) ^ swf));                  \
    s16x8 bf3 = *(const s16x8*)(BB + ((brd[3] + fkb) ^ swf));                  \
    s16x8 bg0 = *(const s16x8*)(BB + ((brd[0] + fkb + 64) ^ swf));             \
    s16x8 bg1 = *(const s16x8*)(BB + ((brd[1] + fkb + 64) ^ swf));             \
    s16x8 bg2 = *(const s16x8*)(BB + ((brd[2] + fkb + 64) ^ swf));             \
    s16x8 bg3 = *(const s16x8*)(BB + ((brd[3] + fkb + 64) ^ swf));             \
    __builtin_amdgcn_s_setprio(1);                                            \
    _Pragma("unroll") for (int m = 0; m < 5; ++m) {                            \
      float4 sa = *(const float4*)(SLB + sfo[m]);                              \
      float4 sb = *(const float4*)(SLB + sfo[m] + 16);                         \
      s16x8 t1, t2;                                                            \
      t1[0] = f2b(fabsf(sa.x - qa.x)); t2[0] = f2b(sa.x * qa.x);               \
      t1[1] = f2b(fabsf(sa.y - qa.y)); t2[1] = f2b(sa.y * qa.y);               \
      t1[2] = f2b(fabsf(sa.z - qa.z)); t2[2] = f2b(sa.z * qa.z);               \
      t1[3] = f2b(fabsf(sa.w - qa.w)); t2[3] = f2b(sa.w * qa.w);               \
      t1[4] = f2b(fabsf(sb.x - qb.x)); t2[4] = f2b(sb.x * qb.x);               \
      t1[5] = f2b(fabsf(sb.y - qb.y)); t2[5] = f2b(sb.y * qb.y);               \
      t1[6] = f2b(fabsf(sb.z - qb.z)); t2[6] = f2b(sb.z * qb.z);               \
      t1[7] = f2b(fabsf(sb.w - qb.w)); t2[7] = f2b(sb.w * qb.w);               \
      acc[m][0] = __builtin_amdgcn_mfma_f32_16x16x32_bf16(t1, bf0, acc[m][0], 0, 0, 0); \
      acc[m][1] = __builtin_amdgcn_mfma_f32_16x16x32_bf16(t1, bf1, acc[m][1], 0, 0, 0); \
      acc[m][2] = __builtin_amdgcn_mfma_f32_16x16x32_bf16(t1, bf2, acc[m][2], 0, 0, 0); \
      acc[m][3] = __builtin_amdgcn_mfma_f32_16x16x32_bf16(t1, bf3, acc[m][3], 0, 0, 0); \
      acc[m][0] = __builtin_amdgcn_mfma_f32_16x16x32_bf16(t2, bg0, acc[m][0], 0, 0, 0); \
      acc[m][1] = __builtin_amdgcn_mfma_f32_16x16x32_bf16(t2, bg1, acc[m][1], 0, 0, 0); \
      acc[m][2] = __builtin_amdgcn_mfma_f32_16x16x32_bf16(t2, bg2, acc[m][2], 0, 0, 0); \
      acc[m][3] = __builtin_amdgcn_mfma_f32_16x16x32_bf16(t2, bg3, acc[m][3], 0, 0, 0); \
    }                                                                          \
    __builtin_amdgcn_s_setprio(0);                                            \
  } while (0)

  // ---- prologue
  STAGE(0, 0);
  DMA_B(0, 0);
  __syncthreads();

  // ---- main loop: 16 pairs, literal buffer indices
  for (int kp = 0; kp < 16; ++kp) {
    const int ks = kp * 2;
    DMA_B(1, (ks + 1) * 32);
    STAGE(1, ks + 1);
    STEP_BODY(0);
    __syncthreads();
    if (kp < 15) {
      DMA_B(0, (ks + 2) * 32);
      STAGE(0, ks + 2);
      STEP_BODY(1);
      __syncthreads();
    } else {
      STEP_BODY(1);
    }
  }

  // ---- epilogue: + a_s + a_q(+b2 folded), tanh, sum over d, reduce, atomicAdd
  const int colb = n0 + wc * 64 + frow;
  const int rgrp = lq * 4;
#pragma unroll
  for (int m = 0; m < 5; ++m) {
    const int s = wr * 5 + m;
#pragma unroll
    for (int r = 0; r < 4; ++r) {
      const int q = q0 + rgrp + r;
      float t = 0.f;
#pragma unroll
      for (int nf = 0; nf < 4; ++nf) {
        const int col = colb + nf * 16;
        float v = acc[m][nf][r] + a[(size_t)(c * 10 + s) * H_ + col] +
                  a[(size_t)(100 + (q < 300 ? q : 299)) * H_ + col];
        t += ftanh(v);
      }
      t += __shfl_xor(t, 1);
      t += __shfl_xor(t, 2);
      t += __shfl_xor(t, 4);
      t += __shfl_xor(t, 8);
      if ((lane & 15) == 0 && q < 300)
        atomicAdd(&logits[(q * 10 + c) * 10 + s], t);
    }
  }
#undef STAGE
#undef DMA_B
#undef STEP_BODY
}

// ---------------------------------------------------------------------------
// Kernel 4: softmax over s, proto, dists. One block per (q,c): 3000 blocks.
// ---------------------------------------------------------------------------
__global__ __launch_bounds__(256) void out_kernel(
    const float* __restrict__ x, const float* __restrict__ logits,
    float* __restrict__ dists) {
  const int q = blockIdx.x / 10;
  const int c = blockIdx.x % 10;
  const int tid = threadIdx.x;
  const int lane = tid & 63;
  const int wave = tid >> 6;
  __shared__ float red[4];

  float l[S_];
  float m = -1e30f;
#pragma unroll
  for (int s = 0; s < S_; ++s) {
    l[s] = logits[(q * 10 + c) * 10 + s];
    m = fmaxf(m, l[s]);
  }
  float sum = 0.f;
  float sc[S_];
#pragma unroll
  for (int s = 0; s < S_; ++s) {
    sc[s] = __expf(l[s] - m);
    sum += sc[s];
  }
  float inv = 1.f / sum;
#pragma unroll
  for (int s = 0; s < S_; ++s) sc[s] *= inv;

  const int qr = (q / 30) * 40 + 10 + (q % 30);
  float part = 0.f;
#pragma unroll
  for (int ii = 0; ii < 4; ++ii) {
    int i = tid + ii * 256;
    float p = 0.f;
#pragma unroll
    for (int s = 0; s < S_; ++s)
      p = fmaf(sc[s], x[(size_t)(c * 40 + s) * H_ + i], p);
    float d = p - x[(size_t)qr * H_ + i];
    part = fmaf(d, d, part);
  }
  for (int off = 32; off; off >>= 1) part += __shfl_down(part, off);
  if (lane == 0) red[wave] = part;
  __syncthreads();
  if (tid == 0) dists[q * 10 + c] = red[0] + red[1] + red[2] + red[3];
}

// ---------------------------------------------------------------------------
extern "C" void kernel_launch(void* const* d_in, const int* in_sizes, int n_in,
                              void* d_out, int out_size, void* d_ws, size_t ws_size,
                              hipStream_t stream) {
  const float* x = (const float*)d_in[0];
  const float* W1 = (const float*)d_in[1];
  const float* b1 = (const float*)d_in[2];
  const float* W2 = (const float*)d_in[3];
  const float* b2 = (const float*)d_in[4];
  float* out = (float*)d_out;

  float* f = (float*)d_ws;                       // 400*1024 f32
  float* a = f + ROWS_ * H_;                     // 400*1024 f32
  float* logits = a + ROWS_ * H_;                // 30000 f32 (+pad)
  unsigned short* Bt = (unsigned short*)(logits + 30208);  // 2 x 1024 x 1024 bf16

  feat_trans_kernel<<<913, 512, 0, stream>>>(x, W1, b1, W2, f, Bt, logits);
  proj_kernel<<<400, 512, 0, stream>>>(f, W2, b2, a);
  mca_mfma_kernel<<<10 * 19 * 8, 256, 0, stream>>>(f, a, Bt, logits);
  out_kernel<<<3000, 256, 0, stream>>>(x, logits, out);
}

// Round 22
// 261.505 us; speedup vs baseline: 1.0625x; 1.0625x over previous
//
#include <hip/hip_runtime.h>
#include <hip/hip_bf16.h>
#include <math.h>

// ProtoInstanceMultiCrossAttention: C=10, S=10, NQ=30, H=1024
#define C_   10
#define S_   10
#define NQ_  30
#define H_   1024
#define Q_   300
#define ROWS_ 400

typedef __attribute__((ext_vector_type(8))) short s16x8;    // 8 bf16 (4 VGPRs)
typedef __attribute__((ext_vector_type(4))) float f32x4;    // MFMA acc

static __device__ __forceinline__ short f2b(float f) {
  __hip_bfloat16 h = __float2bfloat16(f);
  return __builtin_bit_cast(short, h);
}

static __device__ __forceinline__ float ftanh(float v) {
  v = fminf(fmaxf(v, -10.f), 10.f);
  float e = __expf(2.f * v);
  return (e - 1.f) / (e + 1.f);
}

// ---------------------------------------------------------------------------
// Kernel 1 (merged): blocks [0,800): f = x @ W1 + b1 (2-row x 256-col tiles);
// blocks [800,1312): Bt[mat][n][k] = bf16(W[k][n]); block 1312: zero logits.
// feat and trans are independent -> overlap in one launch.
// ---------------------------------------------------------------------------
__global__ __launch_bounds__(256) void feat_trans_kernel(
    const float* __restrict__ x, const float* __restrict__ W1,
    const float* __restrict__ b1, const float* __restrict__ W2,
    float* __restrict__ f, unsigned short* __restrict__ Bt,
    float* __restrict__ logits) {
  __shared__ char lsbuf[64 * 65 * 4];  // overlaid: feat xs[2][1024] / trans tl[64][65]
  const int bi = blockIdx.x;
  const int tid = threadIdx.x;

  if (bi < 800) {
    // ---- feat: f = x @ W1 + b1
    float (*xs)[H_] = (float (*)[H_])lsbuf;
    const int rt = bi % 200;
    const int nt = bi / 200;
    const int r0 = rt * 2;
    const int n0 = nt * 256;

    for (int t = tid; t < 2 * H_ / 4; t += 256) {
      int r = t >> 8, h4 = (t & 255) * 4;
      *(float4*)&xs[r][h4] = *(const float4*)&x[(size_t)(r0 + r) * H_ + h4];
    }
    __syncthreads();

    float acc0 = 0.f, acc1 = 0.f;
    const float* __restrict__ wp = W1 + n0 + tid;
#pragma unroll 16
    for (int h = 0; h < H_; ++h) {
      float w = wp[(size_t)h * H_];
      acc0 = fmaf(xs[0][h], w, acc0);
      acc1 = fmaf(xs[1][h], w, acc1);
    }
    const int col = n0 + tid;
    const float bb = b1[col];
    f[(size_t)(r0 + 0) * H_ + col] = acc0 + bb;
    f[(size_t)(r0 + 1) * H_ + col] = acc1 + bb;
    return;
  }

  if (bi == 1312) {
    float4* lz = (float4*)logits;
    for (int i = tid; i < 7500; i += 256) lz[i] = make_float4(0.f, 0.f, 0.f, 0.f);
    return;
  }

  // ---- trans: Bt[mat][n][k] = bf16(W[k][n])
  {
    float (*tl)[65] = (float (*)[65])lsbuf;
    const int b = bi - 800;
    const int mat = b >> 8, kt = (b >> 4) & 15, ntl = b & 15;
    const float* __restrict__ src =
        W2 + (size_t)(2 + mat) * H_ * H_ + (size_t)(kt * 64) * H_ + ntl * 64;
    {
      int r = tid >> 2, c4 = (tid & 3) * 16;
      const float* srcp = src + (size_t)r * H_ + c4;
#pragma unroll
      for (int j = 0; j < 4; ++j) {
        float4 v = *(const float4*)(srcp + j * 4);
        tl[r][c4 + j * 4 + 0] = v.x;
        tl[r][c4 + j * 4 + 1] = v.y;
        tl[r][c4 + j * 4 + 2] = v.z;
        tl[r][c4 + j * 4 + 3] = v.w;
      }
    }
    __syncthreads();
    {
      int n = tid >> 2, k0t = (tid & 3) * 16;
      s16x8 o0, o1;
#pragma unroll
      for (int j = 0; j < 8; ++j) {
        o0[j] = f2b(tl[k0t + j][n]);
        o1[j] = f2b(tl[k0t + 8 + j][n]);
      }
      unsigned short* dstp = Bt + (size_t)mat * H_ * H_ +
                             (size_t)(ntl * 64 + n) * H_ + kt * 64 + k0t;
      *(s16x8*)dstp = o0;
      *(s16x8*)(dstp + 8) = o1;
    }
  }
}

// ---------------------------------------------------------------------------
// Kernel 2: a_s = sf @ Ws (100 rows), a_q = qf @ Wq + b2 (300 rows).
// Grid 200 row-tiles (2 rows; 50 sup + 150 qry) x 4 col-tiles = 800 blocks.
// ---------------------------------------------------------------------------
__global__ __launch_bounds__(256) void proj_kernel(
    const float* __restrict__ f, const float* __restrict__ W2,
    const float* __restrict__ b2, float* __restrict__ a) {
  __shared__ float fs[2][H_];
  const int rt = blockIdx.x % 200;
  const int nt = blockIdx.x / 200;
  const bool isSup = (rt < 50);
  const int i0 = isSup ? rt * 2 : (rt - 50) * 2;
  const int n0 = nt * 256;
  const float* __restrict__ W = isSup ? W2 : (W2 + (size_t)H_ * H_);
  const int tid = threadIdx.x;

  for (int t = tid; t < 2 * H_ / 4; t += 256) {
    int r = t >> 8, h4 = (t & 255) * 4;
    int i = i0 + r;
    int row = isSup ? ((i / 10) * 40 + (i % 10)) : ((i / 30) * 40 + 10 + (i % 30));
    *(float4*)&fs[r][h4] = *(const float4*)&f[(size_t)row * H_ + h4];
  }
  __syncthreads();

  float acc0 = 0.f, acc1 = 0.f;
  const float* __restrict__ wp = W + n0 + tid;
#pragma unroll 16
  for (int h = 0; h < H_; ++h) {
    float w = wp[(size_t)h * H_];
    acc0 = fmaf(fs[0][h], w, acc0);
    acc1 = fmaf(fs[1][h], w, acc1);
  }
  const int col = n0 + tid;
  const float bb = isSup ? 0.f : b2[col];
  const int o0 = isSup ? i0 : (100 + i0);
  a[(size_t)(o0 + 0) * H_ + col] = acc0 + bb;
  a[(size_t)(o0 + 1) * H_ + col] = acc1 + bb;
}

// ---------------------------------------------------------------------------
// Kernel 3 (dominant): bf16 MFMA fused mca — reg-generated A (R10 structure),
// launch_bounds (256,3): VGPR 84, ~3 blocks/CU.  [best-known: ~186 us]
// ---------------------------------------------------------------------------
__global__ __launch_bounds__(256, 3) void mca_mfma_kernel(
    const float* __restrict__ f, const float* __restrict__ a,
    const unsigned short* __restrict__ Bt, float* __restrict__ logits) {
  const int b = blockIdx.x;
  const int nt = b & 7;
  const int qt = (b >> 3) % 19;
  const int c = (b >> 3) / 19;
  const int q0 = qt * 16;
  const int n0 = nt * 128;

  __shared__ unsigned short Bls[2][128 * 64];  // 2 x 16 KB, XOR-swizzled rows
  __shared__ float sl[2][26][36];              // 2 x 3744 B (144 B rows)

  const int tid = threadIdx.x;
  const int w = tid >> 6, lane = tid & 63;
  const int frow = lane & 15;   // qloc AND D-col
  const int lq = lane >> 4;     // k-segment (8 f32)
  const int wr = w >> 1, wc = w & 1;

  // ---- STAGE: 208 threads, one float4 (26 rows x 32 f32)
  const int str = tid >> 3, sseg = tid & 7;
  int sgrow;
  if (str < 10) sgrow = c * 40 + str;
  else {
    int qg = q0 + (str - 10);
    if (qg > 299) qg = 299;
    sgrow = (qg / 30) * 40 + 10 + (qg % 30);
  }
  const float* fb_stage = f + (size_t)sgrow * H_ + sseg * 4;
  const unsigned st_off = (unsigned)(str * 144 + sseg * 16);

  // ---- sl read offsets (bytes)
  const unsigned qfo = (unsigned)((10 + frow) * 144 + lq * 32);
  unsigned sfo[5];
#pragma unroll
  for (int m = 0; m < 5; ++m) sfo[m] = (unsigned)((wr * 5 + m) * 144 + lq * 32);

  // ---- B DMA setup (linear LDS dest, inverse-swizzled source)
  const int rlo = lane >> 3;
  const int cch = (lane & 7) ^ rlo;
  const unsigned short* bsrc[4];
  unsigned bldso[4];
#pragma unroll
  for (int i = 0; i < 4; ++i) {
    int row = w * 32 + i * 8 + rlo;
    bsrc[i] = Bt + (size_t)(cch >> 2) * H_ * H_ + (size_t)(n0 + row) * H_ +
              (cch & 3) * 8;
    bldso[i] = (unsigned)(w * 4096 + i * 1024);
  }

  // ---- B frag read offsets
  const unsigned fkb = (unsigned)(lq * 16);
  const unsigned swf = (unsigned)((frow & 7) << 4);
  unsigned brd[4];
#pragma unroll
  for (int nf = 0; nf < 4; ++nf) brd[nf] = (unsigned)((wc * 64 + nf * 16 + frow) * 128);

  f32x4 acc[5][4];
#pragma unroll
  for (int m = 0; m < 5; ++m)
#pragma unroll
    for (int nf = 0; nf < 4; ++nf) acc[m][nf] = (f32x4)(0.f);

#define STAGE(SLP, KS)                                                         \
  do {                                                                         \
    if (tid < 208) {                                                           \
      float4 v = *(const float4*)(fb_stage + (KS) * 32);                       \
      *(float4*)((char*)&sl[SLP][0][0] + st_off) = v;                          \
    }                                                                          \
  } while (0)

#define DMA_B(P, KG)                                                           \
  do {                                                                         \
    _Pragma("unroll") for (int i = 0; i < 4; ++i) {                            \
      __builtin_amdgcn_global_load_lds(                                        \
          (const __attribute__((address_space(1))) unsigned int*)(bsrc[i] + (KG)), \
          (__attribute__((address_space(3))) unsigned int*)((char*)&Bls[P][0] + bldso[i]), \
          16, 0, 0);                                                           \
    }                                                                          \
  } while (0)

// One K-step: hoist 8 B-frags; per m generate t1/t2 and consume immediately.
#define STEP_BODY(P)                                                           \
  do {                                                                         \
    const char* SLB = (const char*)&sl[P][0][0];                               \
    const char* BB = (const char*)&Bls[P][0];                                  \
    float4 qa = *(const float4*)(SLB + qfo);                                   \
    float4 qb = *(const float4*)(SLB + qfo + 16);                              \
    s16x8 bf0 = *(const s16x8*)(BB + ((brd[0] + fkb) ^ swf));                  \
    s16x8 bf1 = *(const s16x8*)(BB + ((brd[1] + fkb) ^ swf));                  \
    s16x8 bf2 = *(const s16x8*)(BB + ((brd[2] + fkb) ^ swf));                  \
    s16x8 bf3 = *(const s16x8*)(BB + ((brd[3] + fkb) ^ swf));                  \
    s16x8 bg0 = *(const s16x8*)(BB + ((brd[0] + fkb + 64) ^ swf));             \
    s16x8 bg1 = *(const s16x8*)(BB + ((brd[1] + fkb + 64) ^ swf));             \
    s16x8 bg2 = *(const s16x8*)(BB + ((brd[2] + fkb + 64) ^ swf));             \
    s16x8 bg3 = *(const s16x8*)(BB + ((brd[3] + fkb + 64) ^ swf));             \
    __builtin_amdgcn_s_setprio(1);                                            \
    _Pragma("unroll") for (int m = 0; m < 5; ++m) {                            \
      float4 sa = *(const float4*)(SLB + sfo[m]);                              \
      float4 sb = *(const float4*)(SLB + sfo[m] + 16);                         \
      s16x8 t1, t2;                                                            \
      t1[0] = f2b(fabsf(sa.x - qa.x)); t2[0] = f2b(sa.x * qa.x);               \
      t1[1] = f2b(fabsf(sa.y - qa.y)); t2[1] = f2b(sa.y * qa.y);               \
      t1[2] = f2b(fabsf(sa.z - qa.z)); t2[2] = f2b(sa.z * qa.z);               \
      t1[3] = f2b(fabsf(sa.w - qa.w)); t2[3] = f2b(sa.w * qa.w);               \
      t1[4] = f2b(fabsf(sb.x - qb.x)); t2[4] = f2b(sb.x * qb.x);               \
      t1[5] = f2b(fabsf(sb.y - qb.y)); t2[5] = f2b(sb.y * qb.y);               \
      t1[6] = f2b(fabsf(sb.z - qb.z)); t2[6] = f2b(sb.z * qb.z);               \
      t1[7] = f2b(fabsf(sb.w - qb.w)); t2[7] = f2b(sb.w * qb.w);               \
      acc[m][0] = __builtin_amdgcn_mfma_f32_16x16x32_bf16(t1, bf0, acc[m][0], 0, 0, 0); \
      acc[m][1] = __builtin_amdgcn_mfma_f32_16x16x32_bf16(t1, bf1, acc[m][1], 0, 0, 0); \
      acc[m][2] = __builtin_amdgcn_mfma_f32_16x16x32_bf16(t1, bf2, acc[m][2], 0, 0, 0); \
      acc[m][3] = __builtin_amdgcn_mfma_f32_16x16x32_bf16(t1, bf3, acc[m][3], 0, 0, 0); \
      acc[m][0] = __builtin_amdgcn_mfma_f32_16x16x32_bf16(t2, bg0, acc[m][0], 0, 0, 0); \
      acc[m][1] = __builtin_amdgcn_mfma_f32_16x16x32_bf16(t2, bg1, acc[m][1], 0, 0, 0); \
      acc[m][2] = __builtin_amdgcn_mfma_f32_16x16x32_bf16(t2, bg2, acc[m][2], 0, 0, 0); \
      acc[m][3] = __builtin_amdgcn_mfma_f32_16x16x32_bf16(t2, bg3, acc[m][3], 0, 0, 0); \
    }                                                                          \
    __builtin_amdgcn_s_setprio(0);                                            \
  } while (0)

  // ---- prologue
  STAGE(0, 0);
  DMA_B(0, 0);
  __syncthreads();

  // ---- main loop: 16 pairs, literal buffer indices
  for (int kp = 0; kp < 16; ++kp) {
    const int ks = kp * 2;
    DMA_B(1, (ks + 1) * 32);
    STAGE(1, ks + 1);
    STEP_BODY(0);
    __syncthreads();
    if (kp < 15) {
      DMA_B(0, (ks + 2) * 32);
      STAGE(0, ks + 2);
      STEP_BODY(1);
      __syncthreads();
    } else {
      STEP_BODY(1);
    }
  }

  // ---- epilogue: + a_s + a_q(+b2 folded), tanh, sum over d, reduce, atomicAdd
  const int colb = n0 + wc * 64 + frow;
  const int rgrp = lq * 4;
#pragma unroll
  for (int m = 0; m < 5; ++m) {
    const int s = wr * 5 + m;
#pragma unroll
    for (int r = 0; r < 4; ++r) {
      const int q = q0 + rgrp + r;
      float t = 0.f;
#pragma unroll
      for (int nf = 0; nf < 4; ++nf) {
        const int col = colb + nf * 16;
        float v = acc[m][nf][r] + a[(size_t)(c * 10 + s) * H_ + col] +
                  a[(size_t)(100 + (q < 300 ? q : 299)) * H_ + col];
        t += ftanh(v);
      }
      t += __shfl_xor(t, 1);
      t += __shfl_xor(t, 2);
      t += __shfl_xor(t, 4);
      t += __shfl_xor(t, 8);
      if ((lane & 15) == 0 && q < 300)
        atomicAdd(&logits[(q * 10 + c) * 10 + s], t);
    }
  }
#undef STAGE
#undef DMA_B
#undef STEP_BODY
}

// ---------------------------------------------------------------------------
// Kernel 4: softmax over s, proto, dists. One block per (q,c): 3000 blocks.
// ---------------------------------------------------------------------------
__global__ __launch_bounds__(256) void out_kernel(
    const float* __restrict__ x, const float* __restrict__ logits,
    float* __restrict__ dists) {
  const int q = blockIdx.x / 10;
  const int c = blockIdx.x % 10;
  const int tid = threadIdx.x;
  const int lane = tid & 63;
  const int wave = tid >> 6;
  __shared__ float red[4];

  float l[S_];
  float m = -1e30f;
#pragma unroll
  for (int s = 0; s < S_; ++s) {
    l[s] = logits[(q * 10 + c) * 10 + s];
    m = fmaxf(m, l[s]);
  }
  float sum = 0.f;
  float sc[S_];
#pragma unroll
  for (int s = 0; s < S_; ++s) {
    sc[s] = __expf(l[s] - m);
    sum += sc[s];
  }
  float inv = 1.f / sum;
#pragma unroll
  for (int s = 0; s < S_; ++s) sc[s] *= inv;

  const int qr = (q / 30) * 40 + 10 + (q % 30);
  float part = 0.f;
#pragma unroll
  for (int ii = 0; ii < 4; ++ii) {
    int i = tid + ii * 256;
    float p = 0.f;
#pragma unroll
    for (int s = 0; s < S_; ++s)
      p = fmaf(sc[s], x[(size_t)(c * 40 + s) * H_ + i], p);
    float d = p - x[(size_t)qr * H_ + i];
    part = fmaf(d, d, part);
  }
  for (int off = 32; off; off >>= 1) part += __shfl_down(part, off);
  if (lane == 0) red[wave] = part;
  __syncthreads();
  if (tid == 0) dists[q * 10 + c] = red[0] + red[1] + red[2] + red[3];
}

// ---------------------------------------------------------------------------
extern "C" void kernel_launch(void* const* d_in, const int* in_sizes, int n_in,
                              void* d_out, int out_size, void* d_ws, size_t ws_size,
                              hipStream_t stream) {
  const float* x = (const float*)d_in[0];
  const float* W1 = (const float*)d_in[1];
  const float* b1 = (const float*)d_in[2];
  const float* W2 = (const float*)d_in[3];
  const float* b2 = (const float*)d_in[4];
  float* out = (float*)d_out;

  float* f = (float*)d_ws;                       // 400*1024 f32
  float* a = f + ROWS_ * H_;                     // 400*1024 f32
  float* logits = a + ROWS_ * H_;                // 30000 f32 (+pad)
  unsigned short* Bt = (unsigned short*)(logits + 30208);  // 2 x 1024 x 1024 bf16

  feat_trans_kernel<<<1313, 256, 0, stream>>>(x, W1, b1, W2, f, Bt, logits);
  proj_kernel<<<800, 256, 0, stream>>>(f, W2, b2, a);
  mca_mfma_kernel<<<10 * 19 * 8, 256, 0, stream>>>(f, a, Bt, logits);
  out_kernel<<<3000, 256, 0, stream>>>(x, logits, out);
}